// Round 1
// baseline (223.477 us; speedup 1.0000x reference)
//
#include <hip/hip_runtime.h>

typedef unsigned short u16;
typedef __attribute__((ext_vector_type(8))) short short8;   // 8 bf16 = 4 VGPR (MFMA A/B frag)
typedef __attribute__((ext_vector_type(4))) float f32x4;    // MFMA C/D frag
typedef const __attribute__((address_space(1))) unsigned int g_u32;
typedef __attribute__((address_space(3))) unsigned int l_u32;

#define BATCH 16384
#define XCOLS 2048

__device__ __forceinline__ void gload16(const void* g, void* l) {
  // async global->LDS, 16B/lane; LDS dest = wave-uniform base + lane*16
  __builtin_amdgcn_global_load_lds((g_u32*)g, (l_u32*)l, 16, 0, 0);
}
__device__ __forceinline__ u16 f2bf(float f) {   // RNE f32->bf16
  unsigned int x = __builtin_bit_cast(unsigned int, f);
  x += 0x7fffu + ((x >> 16) & 1u);
  return (u16)(x >> 16);
}
__device__ __forceinline__ float bf2f(u16 u) {
  return __builtin_bit_cast(float, (unsigned int)u << 16);
}
// XOR-swizzle: 16B slot index ^= 128B-line index (involution; kills the
// stride-128B same-bank pattern on ds_read_b128; residual 2-way = free)
__device__ __forceinline__ int swz(int P) { return P ^ (((P >> 7) & 7) << 4); }

__device__ __forceinline__ float fast_tanh(float x) {
  float e2 = __expf(2.0f * x);                       // v_exp_f32
  return 1.0f - 2.0f * __builtin_amdgcn_rcpf(e2 + 1.0f);
}

__device__ const unsigned char PI[21] = {0,0,0,0,0,0,1,1,1,1,1,2,2,2,2,3,3,3,4,4,5};
__device__ const unsigned char PJ[21] = {1,2,3,4,5,6,2,3,4,5,6,3,4,5,6,4,5,6,5,6,6};

// ---------------- prep: ctx f32 -> bf16 into X[:,0:1792] ----------------
__global__ void prep_ctx(const float* __restrict__ ctx, u16* __restrict__ X) {
  const int total = BATCH * 224;                     // 1792/8 octets per row
  for (int u = blockIdx.x * blockDim.x + threadIdx.x; u < total;
       u += gridDim.x * blockDim.x) {
    int b = u / 224, c8 = u - b * 224;
    const float4* s = (const float4*)(ctx + (size_t)b * 1792 + c8 * 8);
    float4 v0 = s[0], v1 = s[1];
    short8 o;
    o[0] = (short)f2bf(v0.x); o[1] = (short)f2bf(v0.y);
    o[2] = (short)f2bf(v0.z); o[3] = (short)f2bf(v0.w);
    o[4] = (short)f2bf(v1.x); o[5] = (short)f2bf(v1.y);
    o[6] = (short)f2bf(v1.z); o[7] = (short)f2bf(v1.w);
    *(short8*)(X + (size_t)b * XCOLS + c8 * 8) = o;
  }
}

// --------- prep: WcT[n][k] (n<256: W_rel[k][n]; else W_rel[256+k][n-256]) ---------
__global__ void prep_wrel(const float* __restrict__ Wr, u16* __restrict__ WcT) {
  int idx = blockIdx.x * 256 + threadIdx.x;          // 512*256
  if (idx >= 512 * 256) return;
  int n = idx >> 8, k = idx & 255;
  float v = (n < 256) ? Wr[k * 256 + n] : Wr[(256 + k) * 256 + (n - 256)];
  WcT[idx] = f2bf(v);
}

// --------- prep: WfcT[n][k] = bf16(W_fc[k][n]), LDS-tiled transpose ---------
__global__ void prep_wfc(const float* __restrict__ W, u16* __restrict__ WT) {
  __shared__ float t[64][65];
  int k0 = blockIdx.x * 64;                          // 32 blocks (K=2048)
  int n0 = blockIdx.y * 64;                          // 16 blocks (N=1024)
  int tx = threadIdx.x & 63, ty = threadIdx.x >> 6;  // 256 thr
  #pragma unroll
  for (int i = 0; i < 64; i += 4)
    t[ty + i][tx] = W[(size_t)(k0 + ty + i) * 1024 + n0 + tx];
  __syncthreads();
  #pragma unroll
  for (int i = 0; i < 64; i += 4) {
    int n = ty + i;
    WT[(size_t)(n0 + n) * XCOLS + k0 + tx] = f2bf(t[tx][n]);
  }
}

// ---------------- fused GEMM-1 + tanh + shuffled pair-sum ----------------
// block: 8 batches (56 real rows padded to 64), N=512, K=256, 512 thr (8 waves 2x4)
__global__ __launch_bounds__(512, 4) void gemm1_fused(u16* X, const u16* __restrict__ WcT,
                                                      const float* __restrict__ b_rel) {
  __shared__ __align__(16) u16 smem[29184];          // 58368B: A 4K|B 32K union UV 56x1024B, brel @57344
  char* sb = (char*)smem;
  const int tid = threadIdx.x;
  const int wid = tid >> 6, lane = tid & 63;
  const int wr = wid >> 2, wc = wid & 3;
  const int b_base = blockIdx.x * 8;
  float* brelL = (float*)(sb + 57344);
  if (tid < 256) brelL[tid] = b_rel[tid];
  f32x4 acc[2][8] = {};
  for (int kt = 0; kt < 8; ++kt) {
    const int kb = kt * 32;
    if (wid < 4) {                                   // stage A: 64x32 bf16 = 4KB
      int L = swz((wid * 64 + lane) * 16);
      int row = L >> 6, koff = (L & 63) >> 1;
      int rowc = row < 56 ? row : 0;                 // pad rows: harmless clamp
      int bl = rowc / 7, e = rowc - bl * 7;
      gload16(X + (size_t)(b_base + bl) * XCOLS + e * 256 + kb + koff, sb + wid * 1024);
    }
    #pragma unroll
    for (int i = 0; i < 4; ++i) {                    // stage B: 512x32 bf16 = 32KB
      int cb = (wid + i * 8) * 64;
      int L = swz((cb + lane) * 16);
      int rn = L >> 6, koff = (L & 63) >> 1;
      gload16(WcT + rn * 256 + kb + koff, sb + 4096 + cb * 16);
    }
    __syncthreads();
    short8 a[2], b[8];
    #pragma unroll
    for (int m = 0; m < 2; ++m) {
      int row = wr * 32 + m * 16 + (lane & 15);
      int L = row * 64 + ((lane >> 4) << 4);
      a[m] = *(const short8*)(sb + swz(L));
    }
    #pragma unroll
    for (int n = 0; n < 8; ++n) {
      int rn = wc * 128 + n * 16 + (lane & 15);
      int L = rn * 64 + ((lane >> 4) << 4);
      b[n] = *(const short8*)(sb + 4096 + swz(L));
    }
    #pragma unroll
    for (int m = 0; m < 2; ++m)
      #pragma unroll
      for (int n = 0; n < 8; ++n)
        acc[m][n] = __builtin_amdgcn_mfma_f32_16x16x32_bf16(a[m], b[n], acc[m][n], 0, 0, 0);
    __syncthreads();
  }
  // stage U/V tile -> LDS bf16, row-based XOR swizzle (rows are 1024B)
  #pragma unroll
  for (int m = 0; m < 2; ++m) {
    int row0 = wr * 32 + m * 16 + ((lane >> 4) << 2);
    #pragma unroll
    for (int n = 0; n < 8; ++n) {
      int col = wc * 128 + n * 16 + (lane & 15);
      #pragma unroll
      for (int v = 0; v < 4; ++v) {
        int row = row0 + v;
        if (row < 56) {
          int L = row * 1024 + col * 2;
          *(u16*)(sb + (L ^ ((row & 7) << 4))) = f2bf(acc[m][n][v]);
        }
      }
    }
  }
  __syncthreads();
  // rel_out[b,r] = sum_c tanh(U[b,I[p],h] + V[b,J[p],h] + b_rel[h]), k=r*21+c
  #pragma unroll
  for (int i = 0; i < 4; ++i) {
    int o = tid + i * 512;
    int bl = o >> 8, r = o & 255;
    float sum = 0.f;
    #pragma unroll
    for (int c = 0; c < 21; ++c) {
      int k = r * 21 + c;
      int p = k >> 8, h = k & 255;
      int ri = bl * 7 + PI[p], rj = bl * 7 + PJ[p];
      int Lu = ri * 1024 + h * 2;
      int Lv = rj * 1024 + 512 + h * 2;
      float uv = bf2f(*(const u16*)(sb + (Lu ^ ((ri & 7) << 4))));
      float vv = bf2f(*(const u16*)(sb + (Lv ^ ((rj & 7) << 4))));
      sum += fast_tanh(uv + vv + brelL[h]);
    }
    X[(size_t)(b_base + bl) * XCOLS + 1792 + r] = f2bf(sum);
  }
}

// ---------------- GEMM-2: out = tanh(X[16384,2048] @ WfcT^T + b_fc) ----------------
// 128x128 tile, BK=64, 256 thr (4 waves 2x2), m97-style loop
__global__ __launch_bounds__(256, 3) void gemm2(const u16* __restrict__ X, const u16* __restrict__ WT,
                                                const float* __restrict__ b_fc, float* __restrict__ out) {
  __shared__ __align__(16) u16 smem[16384];          // A 16KB | B 16KB
  char* sb = (char*)smem;
  const int tid = threadIdx.x;
  const int wid = tid >> 6, lane = tid & 63;
  const int wr = wid >> 1, wc = wid & 1;
  int bid = blockIdx.x;
  int sw = (bid & 7) * 128 + (bid >> 3);             // XCD-contiguous remap (1024%8==0)
  int bm = sw >> 3, bn = sw & 7;
  const size_t mBase = (size_t)bm * 128;
  const int nBase = bn * 128;
  f32x4 acc[4][4] = {};
  for (int kt = 0; kt < 32; ++kt) {
    const int kb = kt * 64;
    #pragma unroll
    for (int i = 0; i < 4; ++i) {
      int cb = (wid + i * 4) * 64;
      int L = swz((cb + lane) * 16);
      int row = L >> 7, koff = (L & 127) >> 1;
      gload16(X + (mBase + row) * XCOLS + kb + koff, sb + cb * 16);
      gload16(WT + (size_t)(nBase + row) * XCOLS + kb + koff, sb + 16384 + cb * 16);
    }
    __syncthreads();
    #pragma unroll
    for (int kk = 0; kk < 64; kk += 32) {
      short8 a[4], b[4];
      #pragma unroll
      for (int m = 0; m < 4; ++m) {
        int row = wr * 64 + m * 16 + (lane & 15);
        int L = row * 128 + kk * 2 + ((lane >> 4) << 4);
        a[m] = *(const short8*)(sb + swz(L));
      }
      #pragma unroll
      for (int n = 0; n < 4; ++n) {
        int rn = wc * 64 + n * 16 + (lane & 15);
        int L = rn * 128 + kk * 2 + ((lane >> 4) << 4);
        b[n] = *(const short8*)(sb + 16384 + swz(L));
      }
      #pragma unroll
      for (int m = 0; m < 4; ++m)
        #pragma unroll
        for (int n = 0; n < 4; ++n)
          acc[m][n] = __builtin_amdgcn_mfma_f32_16x16x32_bf16(a[m], b[n], acc[m][n], 0, 0, 0);
    }
    __syncthreads();
  }
  #pragma unroll
  for (int m = 0; m < 4; ++m) {
    int row0 = wr * 64 + m * 16 + ((lane >> 4) << 2);
    #pragma unroll
    for (int n = 0; n < 4; ++n) {
      int col = nBase + wc * 64 + n * 16 + (lane & 15);
      float bias = b_fc[col];
      #pragma unroll
      for (int v = 0; v < 4; ++v)
        out[(mBase + row0 + v) * 1024 + col] = fast_tanh(acc[m][n][v] + bias);
    }
  }
}

extern "C" void kernel_launch(void* const* d_in, const int* in_sizes, int n_in,
                              void* d_out, int out_size, void* d_ws, size_t ws_size,
                              hipStream_t stream) {
  const float* ctx   = (const float*)d_in[0];
  const float* W_rel = (const float*)d_in[1];
  const float* b_rel = (const float*)d_in[2];
  const float* W_fc  = (const float*)d_in[3];
  const float* b_fc  = (const float*)d_in[4];
  float* out = (float*)d_out;
  // ws layout (71,565,312 B): X bf16 [16384,2048] | WcT bf16 [512,256] | WfcT bf16 [1024,2048]
  u16* X    = (u16*)d_ws;
  u16* WcT  = X + (size_t)BATCH * XCOLS;
  u16* WfcT = WcT + 512 * 256;
  prep_ctx<<<2048, 256, 0, stream>>>(ctx, X);
  prep_wrel<<<512, 256, 0, stream>>>(W_rel, WcT);
  prep_wfc<<<dim3(32, 16), 256, 0, stream>>>(W_fc, WfcT);
  gemm1_fused<<<2048, 512, 0, stream>>>(X, WcT, b_rel);
  gemm2<<<1024, 256, 0, stream>>>(X, WfcT, b_fc, out);
}

// Round 2
// 201.447 us; speedup vs baseline: 1.1094x; 1.1094x over previous
//
#include <hip/hip_runtime.h>

typedef unsigned short u16;
typedef __attribute__((ext_vector_type(8))) short short8;   // 8 bf16 = 4 VGPR (MFMA A/B frag)
typedef __attribute__((ext_vector_type(4))) float f32x4;    // MFMA C/D frag
typedef const __attribute__((address_space(1))) unsigned int g_u32;
typedef __attribute__((address_space(3))) unsigned int l_u32;

#define BATCH 16384
#define XCOLS 2048

__device__ __forceinline__ void gload16(const void* g, void* l) {
  // async global->LDS, 16B/lane; LDS dest = wave-uniform base + lane*16
  __builtin_amdgcn_global_load_lds((g_u32*)g, (l_u32*)l, 16, 0, 0);
}
__device__ __forceinline__ u16 f2bf(float f) {   // RNE f32->bf16
  unsigned int x = __builtin_bit_cast(unsigned int, f);
  x += 0x7fffu + ((x >> 16) & 1u);
  return (u16)(x >> 16);
}
__device__ __forceinline__ float bf2f(u16 u) {
  return __builtin_bit_cast(float, (unsigned int)u << 16);
}
// XOR-swizzle on byte offsets with 128B lines: 16B-slot ^= line&7
__device__ __forceinline__ int swz(int P) { return P ^ (((P >> 7) & 7) << 4); }

__device__ __forceinline__ float fast_tanh(float x) {
  float e2 = __expf(2.0f * x);                       // v_exp_f32
  return 1.0f - 2.0f * __builtin_amdgcn_rcpf(e2 + 1.0f);
}

__device__ const unsigned char PI[21] = {0,0,0,0,0,0,1,1,1,1,1,2,2,2,2,3,3,3,4,4,5};
__device__ const unsigned char PJ[21] = {1,2,3,4,5,6,2,3,4,5,6,3,4,5,6,4,5,6,5,6,6};

// ---------------- prep: ctx f32 -> bf16 into X[:,0:1792] ----------------
__global__ void prep_ctx(const float* __restrict__ ctx, u16* __restrict__ X) {
  const int total = BATCH * 224;                     // 1792/8 octets per row
  for (int u = blockIdx.x * blockDim.x + threadIdx.x; u < total;
       u += gridDim.x * blockDim.x) {
    int b = u / 224, c8 = u - b * 224;
    const float4* s = (const float4*)(ctx + (size_t)b * 1792 + c8 * 8);
    float4 v0 = s[0], v1 = s[1];
    short8 o;
    o[0] = (short)f2bf(v0.x); o[1] = (short)f2bf(v0.y);
    o[2] = (short)f2bf(v0.z); o[3] = (short)f2bf(v0.w);
    o[4] = (short)f2bf(v1.x); o[5] = (short)f2bf(v1.y);
    o[6] = (short)f2bf(v1.z); o[7] = (short)f2bf(v1.w);
    *(short8*)(X + (size_t)b * XCOLS + c8 * 8) = o;
  }
}

// --------- prep: WcT[n][k] (n<256: W_rel[k][n]; else W_rel[256+k][n-256]) ---------
__global__ void prep_wrel(const float* __restrict__ Wr, u16* __restrict__ WcT) {
  int idx = blockIdx.x * 256 + threadIdx.x;          // 512*256
  if (idx >= 512 * 256) return;
  int n = idx >> 8, k = idx & 255;
  float v = (n < 256) ? Wr[k * 256 + n] : Wr[(256 + k) * 256 + (n - 256)];
  WcT[idx] = f2bf(v);
}

// --------- prep: WfcT[n][k] = bf16(W_fc[k][n]), LDS-tiled transpose ---------
__global__ void prep_wfc(const float* __restrict__ W, u16* __restrict__ WT) {
  __shared__ float t[64][65];
  int k0 = blockIdx.x * 64;                          // 32 blocks (K=2048)
  int n0 = blockIdx.y * 64;                          // 16 blocks (N=1024)
  int tx = threadIdx.x & 63, ty = threadIdx.x >> 6;  // 256 thr
  #pragma unroll
  for (int i = 0; i < 64; i += 4)
    t[ty + i][tx] = W[(size_t)(k0 + ty + i) * 1024 + n0 + tx];
  __syncthreads();
  #pragma unroll
  for (int i = 0; i < 64; i += 4) {
    int n = ty + i;
    WT[(size_t)(n0 + n) * XCOLS + k0 + tx] = f2bf(t[tx][n]);
  }
}

// ---------------- fused GEMM-1 + tanh + shuffled pair-sum ----------------
// block: 8 batches (56 rows pad 64), N=512, K=256, BK=64, 512 thr (8 waves 1x8)
// epilogue: 4 rounds x 2 batches; T[k]=tanh(U+V+brel) vectorized, then 21-consecutive sums
__global__ __launch_bounds__(512, 4) void gemm1_fused(u16* __restrict__ X, const u16* __restrict__ WcT,
                                                      const float* __restrict__ b_rel) {
  // 73728 B: GEMM A[0,8192) B[8192,73728) ; epilogue UV[0,14336) T[14336,57344)
  __shared__ __align__(16) u16 smem[36864];
  char* sb = (char*)smem;
  const int tid = threadIdx.x;
  const int wid = tid >> 6, lane = tid & 63;
  const int b_base = blockIdx.x * 8;
  // bias fragment for this thread's output cols (bake brel/2 into both U and V halves)
  float brl[4];
  #pragma unroll
  for (int n = 0; n < 4; ++n)
    brl[n] = 0.5f * b_rel[(wid & 3) * 64 + n * 16 + (lane & 15)];
  f32x4 acc[4][4] = {};
  for (int kt = 0; kt < 4; ++kt) {
    const int kb = kt * 64;
    { // A: 64x64 bf16 = 8KB (rows 128B), 1 gload16/thread
      int L = swz(tid * 16);
      int row = L >> 7, koff = (L & 127) >> 1;
      int r = row < 56 ? row : 55;                   // pad rows clamp
      int bl = r / 7, e = r - bl * 7;
      gload16(X + (size_t)(b_base + bl) * XCOLS + e * 256 + kb + koff, sb + wid * 1024);
    }
    #pragma unroll
    for (int i = 0; i < 8; ++i) {                    // B: 512x64 bf16 = 64KB
      int slot = i * 512 + tid;
      int L = swz(slot * 16);
      int rn = L >> 7, koff = (L & 127) >> 1;
      gload16(WcT + rn * 256 + kb + koff, sb + 8192 + (i * 512 + wid * 64) * 16);
    }
    __syncthreads();
    #pragma unroll
    for (int kk = 0; kk < 64; kk += 32) {
      short8 a[4], b[4];
      #pragma unroll
      for (int m = 0; m < 4; ++m) {
        int row = m * 16 + (lane & 15);
        int L = row * 128 + kk * 2 + ((lane >> 4) << 4);
        a[m] = *(const short8*)(sb + swz(L));
      }
      #pragma unroll
      for (int n = 0; n < 4; ++n) {
        int rn = wid * 64 + n * 16 + (lane & 15);
        int L = rn * 128 + kk * 2 + ((lane >> 4) << 4);
        b[n] = *(const short8*)(sb + 8192 + swz(L));
      }
      #pragma unroll
      for (int m = 0; m < 4; ++m)
        #pragma unroll
        for (int n = 0; n < 4; ++n)
          acc[m][n] = __builtin_amdgcn_mfma_f32_16x16x32_bf16(a[m], b[n], acc[m][n], 0, 0, 0);
    }
    __syncthreads();
  }
  // ---- epilogue: 4 rounds, each = stage 14 UV rows -> tanh T -> 21-sums ----
  for (int rd = 0; rd < 4; ++rd) {
    const int rbase = rd * 14;
    #pragma unroll
    for (int m = 0; m < 4; ++m) {
      int row0 = m * 16 + ((lane >> 4) << 2);
      #pragma unroll
      for (int v = 0; v < 4; ++v) {
        int lr = row0 + v - rbase;
        if (lr >= 0 && lr < 14) {
          #pragma unroll
          for (int n = 0; n < 4; ++n) {
            int col = wid * 64 + n * 16 + (lane & 15);
            int L = lr * 1024 + col * 2;
            *(u16*)(sb + (L ^ ((lr & 7) << 4))) = f2bf(acc[m][n][v] + brl[n]);
          }
        }
      }
    }
    __syncthreads();
    // tanh pass: 2 batches x 5376 / 8 = 1344 b128-tasks
    for (int i = tid; i < 1344; i += 512) {
      int bb = i >= 672;
      int rem = i - bb * 672;
      int k8 = rem * 8;
      int p = k8 >> 8, h = k8 & 255;
      int li = bb * 7 + PI[p], lj = bb * 7 + PJ[p];
      int Lu = li * 1024 + h * 2;
      int Lv = lj * 1024 + 512 + h * 2;
      short8 uu = *(const short8*)(sb + (Lu ^ ((li & 7) << 4)));
      short8 vv = *(const short8*)(sb + (Lv ^ ((lj & 7) << 4)));
      float t[8];
      #pragma unroll
      for (int e = 0; e < 8; ++e)
        t[e] = fast_tanh(bf2f((u16)uu[e]) + bf2f((u16)vv[e]));
      f32x4* T = (f32x4*)(sb + 14336 + bb * 21504 + k8 * 4);
      T[0] = f32x4{t[0], t[1], t[2], t[3]};
      T[1] = f32x4{t[4], t[5], t[6], t[7]};
    }
    __syncthreads();
    { // sum pass: 512 outputs, one per thread; 21 consecutive f32 (gcd(21,32)=1)
      int bb = tid >> 8, r = tid & 255;
      const float* T = (const float*)(sb + 14336 + bb * 21504);
      float s = 0.f;
      #pragma unroll
      for (int c = 0; c < 21; ++c) s += T[r * 21 + c];
      X[(size_t)(b_base + rd * 2 + bb) * XCOLS + 1792 + r] = f2bf(s);
    }
    __syncthreads();
  }
}

// ---------------- GEMM-2: out = tanh(X[16384,2048] @ WfcT^T + b_fc) ----------------
// 128x128 tile, BK=64, 256 thr (4 waves 2x2), m97-style loop
__global__ __launch_bounds__(256, 3) void gemm2(const u16* __restrict__ X, const u16* __restrict__ WT,
                                                const float* __restrict__ b_fc, float* __restrict__ out) {
  __shared__ __align__(16) u16 smem[16384];          // A 16KB | B 16KB
  char* sb = (char*)smem;
  const int tid = threadIdx.x;
  const int wid = tid >> 6, lane = tid & 63;
  const int wr = wid >> 1, wc = wid & 1;
  int bid = blockIdx.x;
  int sw = (bid & 7) * 128 + (bid >> 3);             // XCD-contiguous remap (1024%8==0)
  int bm = sw >> 3, bn = sw & 7;
  const size_t mBase = (size_t)bm * 128;
  const int nBase = bn * 128;
  f32x4 acc[4][4] = {};
  for (int kt = 0; kt < 32; ++kt) {
    const int kb = kt * 64;
    #pragma unroll
    for (int i = 0; i < 4; ++i) {
      int cb = (wid + i * 4) * 64;
      int L = swz((cb + lane) * 16);
      int row = L >> 7, koff = (L & 127) >> 1;
      gload16(X + (mBase + row) * XCOLS + kb + koff, sb + cb * 16);
      gload16(WT + (size_t)(nBase + row) * XCOLS + kb + koff, sb + 16384 + cb * 16);
    }
    __syncthreads();
    #pragma unroll
    for (int kk = 0; kk < 64; kk += 32) {
      short8 a[4], b[4];
      #pragma unroll
      for (int m = 0; m < 4; ++m) {
        int row = wr * 64 + m * 16 + (lane & 15);
        int L = row * 128 + kk * 2 + ((lane >> 4) << 4);
        a[m] = *(const short8*)(sb + swz(L));
      }
      #pragma unroll
      for (int n = 0; n < 4; ++n) {
        int rn = wc * 64 + n * 16 + (lane & 15);
        int L = rn * 128 + kk * 2 + ((lane >> 4) << 4);
        b[n] = *(const short8*)(sb + 16384 + swz(L));
      }
      #pragma unroll
      for (int m = 0; m < 4; ++m)
        #pragma unroll
        for (int n = 0; n < 4; ++n)
          acc[m][n] = __builtin_amdgcn_mfma_f32_16x16x32_bf16(a[m], b[n], acc[m][n], 0, 0, 0);
    }
    __syncthreads();
  }
  #pragma unroll
  for (int m = 0; m < 4; ++m) {
    int row0 = wr * 64 + m * 16 + ((lane >> 4) << 2);
    #pragma unroll
    for (int n = 0; n < 4; ++n) {
      int col = nBase + wc * 64 + n * 16 + (lane & 15);
      float bias = b_fc[col];
      #pragma unroll
      for (int v = 0; v < 4; ++v)
        out[(mBase + row0 + v) * 1024 + col] = fast_tanh(acc[m][n][v] + bias);
    }
  }
}

extern "C" void kernel_launch(void* const* d_in, const int* in_sizes, int n_in,
                              void* d_out, int out_size, void* d_ws, size_t ws_size,
                              hipStream_t stream) {
  const float* ctx   = (const float*)d_in[0];
  const float* W_rel = (const float*)d_in[1];
  const float* b_rel = (const float*)d_in[2];
  const float* W_fc  = (const float*)d_in[3];
  const float* b_fc  = (const float*)d_in[4];
  float* out = (float*)d_out;
  // ws layout: X bf16 [16384,2048] | WcT bf16 [512,256] | WfcT bf16 [1024,2048]
  u16* X    = (u16*)d_ws;
  u16* WcT  = X + (size_t)BATCH * XCOLS;
  u16* WfcT = WcT + 512 * 256;
  prep_ctx<<<2048, 256, 0, stream>>>(ctx, X);
  prep_wrel<<<512, 256, 0, stream>>>(W_rel, WcT);
  prep_wfc<<<dim3(32, 16), 256, 0, stream>>>(W_fc, WfcT);
  gemm1_fused<<<2048, 512, 0, stream>>>(X, WcT, b_rel);
  gemm2<<<1024, 256, 0, stream>>>(X, WfcT, b_fc, out);
}